// Round 1
// baseline (203.215 us; speedup 1.0000x reference)
//
#include <hip/hip_runtime.h>

#define N_CELL 8192
#define N_DRUG 4096

// Output layout (floats):
//   off0 = 0                      : agg_cell_lp [N_CELL][N_DRUG]
//   off1 = N_CELL*N_DRUG          : agg_drug_lp [N_DRUG][N_CELL]
//   off2 = 2*N_CELL*N_DRUG        : self_cell_lp [N_CELL][N_CELL]
//   off3 = off2 + N_CELL*N_CELL   : self_drug_lp [N_DRUG][N_DRUG]

__global__ __launch_bounds__(256) void rowsum_kernel(const float* __restrict__ adj,
                                                     float* __restrict__ rowsum) {
    int row = blockIdx.x;
    const float4* rowp = reinterpret_cast<const float4*>(adj + (size_t)row * N_DRUG);
    float s = 0.f;
#pragma unroll
    for (int i = 0; i < N_DRUG / 4 / 256; ++i) {
        float4 v = rowp[threadIdx.x + i * 256];
        s += (v.x + v.y) + (v.z + v.w);
    }
    // wave64 butterfly reduce
#pragma unroll
    for (int off = 32; off > 0; off >>= 1) s += __shfl_down(s, off, 64);
    __shared__ float lds[4];
    int lane = threadIdx.x & 63, wid = threadIdx.x >> 6;
    if (lane == 0) lds[wid] = s;
    __syncthreads();
    if (threadIdx.x == 0) rowsum[row] = (lds[0] + lds[1]) + (lds[2] + lds[3]);
}

__global__ __launch_bounds__(256) void colsum_kernel(const float* __restrict__ adj,
                                                     float* __restrict__ colsum) {
    // grid (N_DRUG/256, 32): each block sums a 256-col x 256-row tile.
    int col = blockIdx.x * 256 + threadIdx.x;
    int r0 = blockIdx.y * (N_CELL / 32);
    const float* p = adj + (size_t)r0 * N_DRUG + col;
    float s = 0.f;
#pragma unroll 8
    for (int r = 0; r < N_CELL / 32; ++r) {
        s += p[(size_t)r * N_DRUG];
    }
    atomicAdd(&colsum[col], s);
}

__global__ __launch_bounds__(256) void scale_transpose_kernel(
        const float* __restrict__ adj,
        const float* __restrict__ rowsum,
        const float* __restrict__ colsum,
        float* __restrict__ agg_cell,
        float* __restrict__ agg_drug) {
    __shared__ float tile[64][65];  // +1 pad: conflict-free transposed read
    int tx = threadIdx.x & 63;
    int ty = threadIdx.x >> 6;
    int c0 = blockIdx.x * 64;
    int r0 = blockIdx.y * 64;
    float dy = rsqrtf(colsum[c0 + tx] + 1.0f);
#pragma unroll
    for (int k = 0; k < 16; ++k) {
        int r = r0 + k * 4 + ty;
        float dx = rsqrtf(rowsum[r] + 1.0f);
        size_t idx = (size_t)r * N_DRUG + c0 + tx;
        float v = adj[idx] * dx * dy;
        agg_cell[idx] = v;              // coalesced direct write
        tile[k * 4 + ty][tx] = v;       // stage for transpose
    }
    __syncthreads();
#pragma unroll
    for (int k = 0; k < 16; ++k) {
        int dr = k * 4 + ty;            // drug row within tile
        // agg_drug[c0+dr][r0+tx] — coalesced across tx
        agg_drug[(size_t)(c0 + dr) * N_CELL + r0 + tx] = tile[tx][dr];
    }
}

__global__ __launch_bounds__(256) void diag_kernel(const float* __restrict__ rowsum,
                                                   const float* __restrict__ colsum,
                                                   float* __restrict__ out) {
    const size_t off2 = 2ull * N_CELL * N_DRUG;
    const size_t off3 = off2 + (size_t)N_CELL * N_CELL;
    int i = blockIdx.x * 256 + threadIdx.x;
    if (i < N_CELL) {
        out[off2 + (size_t)i * (N_CELL + 1)] = 1.0f / (rowsum[i] + 1.0f) + 1.0f;
    }
    if (i < N_DRUG) {
        out[off3 + (size_t)i * (N_DRUG + 1)] = 1.0f / (colsum[i] + 1.0f) + 1.0f;
    }
}

extern "C" void kernel_launch(void* const* d_in, const int* in_sizes, int n_in,
                              void* d_out, int out_size, void* d_ws, size_t ws_size,
                              hipStream_t stream) {
    const float* adj = (const float*)d_in[0];
    float* out = (float*)d_out;

    float* rowsum = (float*)d_ws;           // N_CELL floats
    float* colsum = rowsum + N_CELL;        // N_DRUG floats

    const size_t off1 = (size_t)N_CELL * N_DRUG;
    const size_t off2 = 2ull * N_CELL * N_DRUG;
    const size_t off3 = off2 + (size_t)N_CELL * N_CELL;

    // colsum accumulates via atomics -> zero it every call.
    hipMemsetAsync(colsum, 0, N_DRUG * sizeof(float), stream);
    // Diagonal matrices are ~all zeros; harness poisons d_out, so zero every call.
    hipMemsetAsync(out + off2, 0, (size_t)N_CELL * N_CELL * sizeof(float), stream);
    hipMemsetAsync(out + off3, 0, (size_t)N_DRUG * N_DRUG * sizeof(float), stream);

    rowsum_kernel<<<N_CELL, 256, 0, stream>>>(adj, rowsum);
    colsum_kernel<<<dim3(N_DRUG / 256, 32), 256, 0, stream>>>(adj, colsum);
    scale_transpose_kernel<<<dim3(N_DRUG / 64, N_CELL / 64), 256, 0, stream>>>(
        adj, rowsum, colsum, out, out + off1);
    diag_kernel<<<(N_CELL + 255) / 256, 256, 0, stream>>>(rowsum, colsum, out);
}

// Round 3
// 162.119 us; speedup vs baseline: 1.2535x; 1.2535x over previous
//
#include <hip/hip_runtime.h>

#define N_CELL 8192
#define N_DRUG 4096

typedef float f32x4 __attribute__((ext_vector_type(4)));

// Output layout (floats):
//   0                       : agg_cell_lp [N_CELL][N_DRUG]
//   OFF1 = N_CELL*N_DRUG    : agg_drug_lp [N_DRUG][N_CELL]
//   OFF2 = 2*N_CELL*N_DRUG  : self_cell_lp [N_CELL][N_CELL]
//   OFF3 = OFF2 + N_CELL^2  : self_drug_lp [N_DRUG][N_DRUG]
static constexpr size_t OFF1 = (size_t)N_CELL * N_DRUG;
static constexpr size_t OFF2 = 2ull * N_CELL * N_DRUG;
static constexpr size_t OFF3 = OFF2 + (size_t)N_CELL * N_CELL;
static constexpr size_t FILL_F4 = ((size_t)N_CELL * N_CELL + (size_t)N_DRUG * N_DRUG) / 4; // 20,971,520

#define SUM_BLOCKS 512     // 4 col-blocks x 128 row-blocks, tile = 1024 cols x 64 rows
#define FILL_BLOCKS 1536
#define MEGA_BLOCKS (SUM_BLOCKS + FILL_BLOCKS)

// One dispatch, two roles:
//  - blocks [0,512):  fused row+col sums, reading adj exactly once
//  - blocks [512,2048): zero-fill both self matrices with NON-TEMPORAL stores
//    (bypass L3 so adj stays resident for the scale kernel's re-read)
__global__ __launch_bounds__(256) void mega_kernel(const float* __restrict__ adj,
                                                   float* __restrict__ rowsum,
                                                   float* __restrict__ colsum,
                                                   float* __restrict__ fill_base) {
    int b = blockIdx.x;
    int tid = threadIdx.x;
    if (b >= SUM_BLOCKS) {
        f32x4 z = {0.f, 0.f, 0.f, 0.f};
        f32x4* p = reinterpret_cast<f32x4*>(fill_base);
        for (size_t i = (size_t)(b - SUM_BLOCKS) * 256 + tid; i < FILL_F4;
             i += (size_t)FILL_BLOCKS * 256) {
            __builtin_nontemporal_store(z, p + i);
        }
        return;
    }
    // --- sums role ---
    __shared__ float lds_row[64][4];
    int cb = b & 3;    // col block 0..3   -> 1024 cols
    int rb = b >> 2;   // row block 0..127 -> 64 rows
    int c0 = cb * 1024;
    int r0 = rb * 64;
    int lane = tid & 63, w = tid >> 6;
    const f32x4* ap = reinterpret_cast<const f32x4*>(adj + (size_t)r0 * N_DRUG + c0) + tid;
    f32x4 cacc = {0.f, 0.f, 0.f, 0.f};
#pragma unroll 4
    for (int r = 0; r < 64; ++r) {
        f32x4 v = ap[(size_t)r * (N_DRUG / 4)];
        cacc += v;
        float h = (v.x + v.y) + (v.z + v.w);
#pragma unroll
        for (int off = 32; off > 0; off >>= 1) h += __shfl_down(h, off, 64);
        if (lane == 0) lds_row[r][w] = h;
    }
    __syncthreads();
    if (tid < 64) {
        float s = (lds_row[tid][0] + lds_row[tid][1]) + (lds_row[tid][2] + lds_row[tid][3]);
        atomicAdd(&rowsum[r0 + tid], s);   // 4 atomics per row total (one per col-block)
    }
    int c = c0 + tid * 4;
    atomicAdd(&colsum[c + 0], cacc.x);     // 128 atomics per col (one per row-block)
    atomicAdd(&colsum[c + 1], cacc.y);
    atomicAdd(&colsum[c + 2], cacc.z);
    atomicAdd(&colsum[c + 3], cacc.w);
}

// 64x64 tile: f32x4 reads of adj (expect L3-hot), nt f32x4 writes of agg_cell,
// LDS transpose with pad 69, nt f32x4 writes of agg_drug. Diag writes folded
// into the by==0 block row.
__global__ __launch_bounds__(256) void scale_kernel(const float* __restrict__ adj,
                                                    const float* __restrict__ rowsum,
                                                    const float* __restrict__ colsum,
                                                    float* __restrict__ out) {
    __shared__ float tile[64][69];
    int tid = threadIdx.x;
    int tx = tid & 15;   // 16 x f32x4 = 64 cols
    int ty = tid >> 4;   // 16 rows per pass
    int c0 = blockIdx.x * 64;
    int r0 = blockIdx.y * 64;

    if (blockIdx.y == 0) {  // diag fold-in: 64 blocks x 256 threads >= 12288 diag elems
        int gid = blockIdx.x * 256 + tid;
        if (gid < N_CELL) {
            out[OFF2 + (size_t)gid * (N_CELL + 1)] = 1.0f / (rowsum[gid] + 1.0f) + 1.0f;
        } else if (gid < N_CELL + N_DRUG) {
            int j = gid - N_CELL;
            out[OFF3 + (size_t)j * (N_DRUG + 1)] = 1.0f / (colsum[j] + 1.0f) + 1.0f;
        }
    }

    f32x4 cs = *reinterpret_cast<const f32x4*>(colsum + c0 + tx * 4);
    f32x4 dy;
    dy.x = rsqrtf(cs.x + 1.0f);
    dy.y = rsqrtf(cs.y + 1.0f);
    dy.z = rsqrtf(cs.z + 1.0f);
    dy.w = rsqrtf(cs.w + 1.0f);

#pragma unroll
    for (int q = 0; q < 4; ++q) {
        int rr = q * 16 + ty;
        int r = r0 + rr;
        float dx = rsqrtf(rowsum[r] + 1.0f);
        f32x4 v = *reinterpret_cast<const f32x4*>(adj + (size_t)r * N_DRUG + c0 + tx * 4);
        f32x4 o = v * dx;
        o *= dy;
        __builtin_nontemporal_store(
            o, reinterpret_cast<f32x4*>(out + (size_t)r * N_DRUG + c0 + tx * 4));
        tile[rr][tx * 4 + 0] = o.x;
        tile[rr][tx * 4 + 1] = o.y;
        tile[rr][tx * 4 + 2] = o.z;
        tile[rr][tx * 4 + 3] = o.w;
    }
    __syncthreads();
    float* aggd = out + OFF1;
#pragma unroll
    for (int q = 0; q < 4; ++q) {
        int dr = q * 16 + ty;  // drug index within tile
        f32x4 o;
        o.x = tile[tx * 4 + 0][dr];
        o.y = tile[tx * 4 + 1][dr];
        o.z = tile[tx * 4 + 2][dr];
        o.w = tile[tx * 4 + 3][dr];
        __builtin_nontemporal_store(
            o, reinterpret_cast<f32x4*>(aggd + (size_t)(c0 + dr) * N_CELL + r0 + tx * 4));
    }
}

extern "C" void kernel_launch(void* const* d_in, const int* in_sizes, int n_in,
                              void* d_out, int out_size, void* d_ws, size_t ws_size,
                              hipStream_t stream) {
    const float* adj = (const float*)d_in[0];
    float* out = (float*)d_out;
    float* rowsum = (float*)d_ws;        // N_CELL floats
    float* colsum = rowsum + N_CELL;     // N_DRUG floats

    // zero the atomic accumulators (contiguous 48 KB)
    (void)hipMemsetAsync(d_ws, 0, (N_CELL + N_DRUG) * sizeof(float), stream);

    mega_kernel<<<MEGA_BLOCKS, 256, 0, stream>>>(adj, rowsum, colsum, out + OFF2);
    scale_kernel<<<dim3(N_DRUG / 64, N_CELL / 64), 256, 0, stream>>>(adj, rowsum, colsum, out);
}